// Round 1
// baseline (173.197 us; speedup 1.0000x reference)
//
#include <hip/hip_runtime.h>
#include <math.h>

// ---------------------------------------------------------------------------
// MHLA: LN -> lowrank QKV -> 8-head attention (T=2048, Dh=32) -> Oproj+res
// Round 1: bf16 MFMA throughout. 4 kernels:
//  k0: effective weights  Wq=q_b*q_a (256x256), Wk=k_w*kv_a, Wv=v_w*kv_a (bf16)
//  k1: LN + QKV GEMM (scale*log2e folded into q)
//  k2: flash attention, S^T orientation so P round-trip is b64-write/b128-read
//  k3: o-proj + gamma + residual
// ---------------------------------------------------------------------------

typedef __bf16          bf16x8 __attribute__((ext_vector_type(8)));
typedef float           f32x4  __attribute__((ext_vector_type(4)));
typedef unsigned short  u16x8  __attribute__((ext_vector_type(8)));

#define MFMA16(a,b,c) __builtin_amdgcn_mfma_f32_16x16x32_bf16((a),(b),(c),0,0,0)

#if __has_builtin(__builtin_amdgcn_exp2f)
#define EXP2F(x) __builtin_amdgcn_exp2f(x)
#else
#define EXP2F(x) exp2f(x)
#endif

#define BATCH 4
#define SEQ   2048
#define CMOD  256
#define NH    8
#define DH    32
#define QR    32
#define KVR   64
#define LN_EPS 1e-5f

// ws byte offsets
#define OFF_W    0u          // bf16 [768][256]  q,k,v effective weights
#define OFF_OW   393216u     // bf16 [256][256]  o_w
#define OFF_BIAS 524288u     // f32  [768]       effective biases
#define OFF_Q    528384u     // bf16 [8192][256] (pre-scaled by 1/sqrt(Dh)*log2e)
#define OFF_K    4722688u    // bf16 [8192][256]
#define OFF_V    8916992u    // bf16 [8192][256]
#define OFF_Y    13111296u   // bf16 [8192][256]

__device__ __forceinline__ unsigned short f2bf(float f) {
  unsigned u = __builtin_bit_cast(unsigned, f);
  u = u + 0x7FFFu + ((u >> 16) & 1u);          // RNE
  return (unsigned short)(u >> 16);
}

// ---------------- K0: effective weights ----------------
__global__ __launch_bounds__(256) void k0_weights(
    const float* __restrict__ q_a, const float* __restrict__ q_bias,
    const float* __restrict__ q_b, const float* __restrict__ kv_a,
    const float* __restrict__ kv_bias, const float* __restrict__ k_w,
    const float* __restrict__ v_w, const float* __restrict__ o_w,
    unsigned short* __restrict__ W, unsigned short* __restrict__ OW,
    float* __restrict__ bias_eff) {
  int tid = blockIdx.x * 256 + threadIdx.x;   // 0..65535
  int o = tid >> 8, c = tid & 255;
  float aq = 0.f, ak = 0.f, av = 0.f;
#pragma unroll 8
  for (int r = 0; r < QR; ++r) aq += q_b[o * QR + r] * q_a[r * CMOD + c];
#pragma unroll 8
  for (int r = 0; r < KVR; ++r) {
    float kvac = kv_a[r * CMOD + c];
    ak += k_w[o * KVR + r] * kvac;
    av += v_w[o * KVR + r] * kvac;
  }
  W[o * CMOD + c]           = f2bf(aq);
  W[(256 + o) * CMOD + c]   = f2bf(ak);
  W[(512 + o) * CMOD + c]   = f2bf(av);
  OW[o * CMOD + c]          = f2bf(o_w[o * CMOD + c]);
  if (tid < 256) {
    float s = 0.f;
    for (int r = 0; r < QR; ++r) s += q_b[tid * QR + r] * q_bias[r];
    bias_eff[tid] = s;
  } else if (tid < 512) {
    int oo = tid - 256; float s = 0.f;
    for (int r = 0; r < KVR; ++r) s += k_w[oo * KVR + r] * kv_bias[r];
    bias_eff[tid] = s;
  } else if (tid < 768) {
    int oo = tid - 512; float s = 0.f;
    for (int r = 0; r < KVR; ++r) s += v_w[oo * KVR + r] * kv_bias[r];
    bias_eff[tid] = s;
  }
}

// ---------------- K1: LN + QKV GEMM ----------------
// block: 32 tokens x 768 outputs, 4 waves (each N=192), K=256
#define K1_STR 264   // padded LDS stride (bf16 elems): breaks bank conflicts, keeps 16B align
__global__ __launch_bounds__(256) void k1_ln_qkv(
    const float* __restrict__ x, const float* __restrict__ norm_w,
    const unsigned short* __restrict__ W, const float* __restrict__ bias_eff,
    unsigned short* __restrict__ qws, unsigned short* __restrict__ kws,
    unsigned short* __restrict__ vws) {
  __shared__ unsigned short xn[32 * K1_STR];
  const int tid = threadIdx.x;
  const int token0 = blockIdx.x * 32;
  {
    int row = tid >> 3, ci = (tid & 7) * 32;
    const float* xr = x + (token0 + row) * CMOD + ci;
    float vals[32];
    float sum = 0.f, ss = 0.f;
#pragma unroll
    for (int u = 0; u < 8; ++u) {
      float4 v4 = *(const float4*)(xr + 4 * u);
      vals[4*u+0] = v4.x; vals[4*u+1] = v4.y; vals[4*u+2] = v4.z; vals[4*u+3] = v4.w;
      sum += v4.x + v4.y + v4.z + v4.w;
      ss  += v4.x*v4.x + v4.y*v4.y + v4.z*v4.z + v4.w*v4.w;
    }
#pragma unroll
    for (int m = 1; m <= 4; m <<= 1) { sum += __shfl_xor(sum, m); ss += __shfl_xor(ss, m); }
    float mean = sum * (1.f / 256.f);
    float var  = ss  * (1.f / 256.f) - mean * mean;
    float rstd = rsqrtf(var + LN_EPS);
    unsigned short* dst = xn + row * K1_STR + ci;
#pragma unroll
    for (int u = 0; u < 8; ++u) {
      float4 g4 = *(const float4*)(norm_w + ci + 4 * u);
      unsigned short h0 = f2bf((vals[4*u+0] - mean) * rstd * g4.x);
      unsigned short h1 = f2bf((vals[4*u+1] - mean) * rstd * g4.y);
      unsigned short h2 = f2bf((vals[4*u+2] - mean) * rstd * g4.z);
      unsigned short h3 = f2bf((vals[4*u+3] - mean) * rstd * g4.w);
      uint2 pk;
      pk.x = (unsigned)h0 | ((unsigned)h1 << 16);
      pk.y = (unsigned)h2 | ((unsigned)h3 << 16);
      *(uint2*)(dst + 4 * u) = pk;
    }
  }
  __syncthreads();
  const int l = tid & 63, w = tid >> 6;
  const int li = l & 15, quad = l >> 4;
  const int nbase = w * 192;
  f32x4 acc[2][12];
#pragma unroll
  for (int mb = 0; mb < 2; ++mb)
#pragma unroll
    for (int nb = 0; nb < 12; ++nb) acc[mb][nb] = (f32x4){0.f, 0.f, 0.f, 0.f};
#pragma unroll
  for (int kk = 0; kk < 8; ++kk) {
    bf16x8 a0 = *(const bf16x8*)(xn + (0  + li) * K1_STR + kk * 32 + quad * 8);
    bf16x8 a1 = *(const bf16x8*)(xn + (16 + li) * K1_STR + kk * 32 + quad * 8);
#pragma unroll
    for (int nb = 0; nb < 12; ++nb) {
      int o = nbase + nb * 16 + li;
      bf16x8 bfr = *(const bf16x8*)(W + o * CMOD + kk * 32 + quad * 8);
      acc[0][nb] = MFMA16(a0, bfr, acc[0][nb]);
      acc[1][nb] = MFMA16(a1, bfr, acc[1][nb]);
    }
  }
  // fold softmax scale AND log2(e) into q so attention can use raw exp2
  const float QSC = 0.17677669529663689f * 1.4426950408889634f;
#pragma unroll
  for (int nb = 0; nb < 12; ++nb) {
    int o0 = nbase + nb * 16;
    int o  = o0 + li;
    float bias = bias_eff[o];
    unsigned short* dst; int ch; float sc;
    if (o0 < 256)      { dst = qws; ch = o;       sc = QSC; }
    else if (o0 < 512) { dst = kws; ch = o - 256; sc = 1.f; }
    else               { dst = vws; ch = o - 512; sc = 1.f; }
#pragma unroll
    for (int mb = 0; mb < 2; ++mb)
#pragma unroll
      for (int r = 0; r < 4; ++r) {
        int row = token0 + mb * 16 + quad * 4 + r;
        dst[row * CMOD + ch] = f2bf((acc[mb][nb][r] + bias) * sc);
      }
  }
}

// ---------------- K2: flash attention ----------------
// grid (16 qtiles, 32 b*h), 256 thr. Block = 128 queries; wave owns 32 queries.
// S^T = K(A) * Q(B): C layout => col=query, row=key -> P packs as b64, reads b128.
#define KSTR 40
#define VSTR 136
#define PSTR 136
__global__ __launch_bounds__(256) void k2_attn(
    const unsigned short* __restrict__ qws, const unsigned short* __restrict__ kws,
    const unsigned short* __restrict__ vws, unsigned short* __restrict__ yws) {
  __shared__ unsigned short Kb[128 * KSTR];   // [key][d] padded
  __shared__ unsigned short VT[32 * VSTR];    // [d][key] padded
  __shared__ unsigned short Pb[4][32 * PSTR]; // per-wave [query][key] padded
  __shared__ float albuf[4][32];
  __shared__ float lbuf[4][32];
  const int tid = threadIdx.x;
  const int qt = blockIdx.x, bh = blockIdx.y;
  const int b = bh >> 3, h = bh & 7;
  const int l = tid & 63, w = tid >> 6, li = l & 15, quad = l >> 4;

  bf16x8 qf[2];
#pragma unroll
  for (int nb = 0; nb < 2; ++nb) {
    int tok = b * SEQ + qt * 128 + w * 32 + nb * 16 + li;
    qf[nb] = *(const bf16x8*)(qws + tok * CMOD + h * DH + quad * 8);
  }
  f32x4 O[2][2];
#pragma unroll
  for (int i = 0; i < 2; ++i)
#pragma unroll
    for (int j = 0; j < 2; ++j) O[i][j] = (f32x4){0.f, 0.f, 0.f, 0.f};
  float m_run[2] = {-INFINITY, -INFINITY};
  float l_run[2] = {0.f, 0.f};

  for (int kt = 0; kt < 16; ++kt) {
    // ---- stage K tile [128][32] and V^T tile [32][128] ----
#pragma unroll
    for (int it = 0; it < 2; ++it) {
      int idx = it * 256 + tid;
      int key = idx >> 2, cc = (idx & 3) * 8;
      int tok = b * SEQ + kt * 128 + key;
      u16x8 k8 = *(const u16x8*)(kws + tok * CMOD + h * DH + cc);
      *(u16x8*)(Kb + key * KSTR + cc) = k8;
      u16x8 v8 = *(const u16x8*)(vws + tok * CMOD + h * DH + cc);
#pragma unroll
      for (int j = 0; j < 8; ++j) VT[(cc + j) * VSTR + key] = v8[j];
    }
    __syncthreads();
    // ---- S^T: A=K frags, B=Q frags ----
    bf16x8 kf[8];
#pragma unroll
    for (int mb = 0; mb < 8; ++mb)
      kf[mb] = *(const bf16x8*)(Kb + (mb * 16 + li) * KSTR + quad * 8);
    f32x4 s[8][2];
#pragma unroll
    for (int mb = 0; mb < 8; ++mb)
#pragma unroll
      for (int nb = 0; nb < 2; ++nb)
        s[mb][nb] = MFMA16(kf[mb], qf[nb], ((f32x4){0.f, 0.f, 0.f, 0.f}));
    // ---- online softmax per query(col) ----
#pragma unroll
    for (int nb = 0; nb < 2; ++nb) {
      float mt = -1e30f;
#pragma unroll
      for (int mb = 0; mb < 8; ++mb)
#pragma unroll
        for (int r = 0; r < 4; ++r) mt = fmaxf(mt, s[mb][nb][r]);
      mt = fmaxf(mt, __shfl_xor(mt, 16));
      mt = fmaxf(mt, __shfl_xor(mt, 32));
      float mn = fmaxf(m_run[nb], mt);
      float al = EXP2F(m_run[nb] - mn);       // scores are log2-domain (folded in k1)
      float ts = 0.f;
#pragma unroll
      for (int mb = 0; mb < 8; ++mb) {
#pragma unroll
        for (int r = 0; r < 4; ++r) {
          float e = EXP2F(s[mb][nb][r] - mn);
          s[mb][nb][r] = e;
          ts += e;
        }
      }
      ts += __shfl_xor(ts, 16);
      ts += __shfl_xor(ts, 32);
      l_run[nb] = l_run[nb] * al + ts;
      m_run[nb] = mn;
      albuf[w][nb * 16 + li] = al;            // quads write same value: benign
      // P -> LDS, 4 consecutive keys packed per b64
#pragma unroll
      for (int mb = 0; mb < 8; ++mb) {
        unsigned short h0 = f2bf(s[mb][nb][0]);
        unsigned short h1 = f2bf(s[mb][nb][1]);
        unsigned short h2 = f2bf(s[mb][nb][2]);
        unsigned short h3 = f2bf(s[mb][nb][3]);
        uint2 pk;
        pk.x = (unsigned)h0 | ((unsigned)h1 << 16);
        pk.y = (unsigned)h2 | ((unsigned)h3 << 16);
        *(uint2*)(Pb[w] + (nb * 16 + li) * PSTR + mb * 16 + quad * 4) = pk;
      }
    }
    // ---- rescale O by alpha (per query row) ----
#pragma unroll
    for (int mbq = 0; mbq < 2; ++mbq) {
      f32x4 al4 = *(const f32x4*)&albuf[w][mbq * 16 + quad * 4];
#pragma unroll
      for (int nbd = 0; nbd < 2; ++nbd)
#pragma unroll
        for (int r = 0; r < 4; ++r) O[mbq][nbd][r] *= al4[r];
    }
    // ---- PV: A=P (b128 from Pb), B=V^T (b128 from VT) ----
#pragma unroll
    for (int kk = 0; kk < 4; ++kk) {
      bf16x8 pa0 = *(const bf16x8*)(Pb[w] + (0  + li) * PSTR + kk * 32 + quad * 8);
      bf16x8 pa1 = *(const bf16x8*)(Pb[w] + (16 + li) * PSTR + kk * 32 + quad * 8);
      bf16x8 vb0 = *(const bf16x8*)(VT + (0  + li) * VSTR + kk * 32 + quad * 8);
      bf16x8 vb1 = *(const bf16x8*)(VT + (16 + li) * VSTR + kk * 32 + quad * 8);
      O[0][0] = MFMA16(pa0, vb0, O[0][0]);
      O[0][1] = MFMA16(pa0, vb1, O[0][1]);
      O[1][0] = MFMA16(pa1, vb0, O[1][0]);
      O[1][1] = MFMA16(pa1, vb1, O[1][1]);
    }
    __syncthreads();   // protect Kb/VT for next tile
  }
  lbuf[w][li]      = l_run[0];
  lbuf[w][16 + li] = l_run[1];
#pragma unroll
  for (int mbq = 0; mbq < 2; ++mbq) {
    f32x4 l4 = *(const f32x4*)&lbuf[w][mbq * 16 + quad * 4];
#pragma unroll
    for (int nbd = 0; nbd < 2; ++nbd) {
      int ch = h * DH + nbd * 16 + li;
#pragma unroll
      for (int r = 0; r < 4; ++r) {
        int tok = b * SEQ + qt * 128 + w * 32 + mbq * 16 + quad * 4 + r;
        yws[tok * CMOD + ch] = f2bf(O[mbq][nbd][r] / l4[r]);
      }
    }
  }
}

// ---------------- K3: o-proj + gamma + residual ----------------
#define K3_STR 264
__global__ __launch_bounds__(256) void k3_oproj(
    const unsigned short* __restrict__ yws, const unsigned short* __restrict__ ow,
    const float* __restrict__ x, const float* __restrict__ gamma,
    float* __restrict__ out) {
  __shared__ unsigned short yb[32 * K3_STR];
  const int tid = threadIdx.x;
  const int token0 = blockIdx.x * 32;
  {
    int row = tid >> 3, ci = (tid & 7) * 32;
#pragma unroll
    for (int u = 0; u < 4; ++u) {
      u16x8 v8 = *(const u16x8*)(yws + (token0 + row) * CMOD + ci + 8 * u);
      *(u16x8*)(yb + row * K3_STR + ci + 8 * u) = v8;
    }
  }
  __syncthreads();
  const int l = tid & 63, w = tid >> 6, li = l & 15, quad = l >> 4;
  f32x4 acc[2][4];
#pragma unroll
  for (int mb = 0; mb < 2; ++mb)
#pragma unroll
    for (int nb = 0; nb < 4; ++nb) acc[mb][nb] = (f32x4){0.f, 0.f, 0.f, 0.f};
#pragma unroll
  for (int kk = 0; kk < 8; ++kk) {
    bf16x8 a0 = *(const bf16x8*)(yb + (0  + li) * K3_STR + kk * 32 + quad * 8);
    bf16x8 a1 = *(const bf16x8*)(yb + (16 + li) * K3_STR + kk * 32 + quad * 8);
#pragma unroll
    for (int nb = 0; nb < 4; ++nb) {
      int d = w * 64 + nb * 16 + li;
      bf16x8 bfr = *(const bf16x8*)(ow + d * CMOD + kk * 32 + quad * 8);
      acc[0][nb] = MFMA16(a0, bfr, acc[0][nb]);
      acc[1][nb] = MFMA16(a1, bfr, acc[1][nb]);
    }
  }
#pragma unroll
  for (int nb = 0; nb < 4; ++nb) {
    int d = w * 64 + nb * 16 + li;
    float g = gamma[d];
#pragma unroll
    for (int mb = 0; mb < 2; ++mb)
#pragma unroll
      for (int r = 0; r < 4; ++r) {
        int tok = token0 + mb * 16 + quad * 4 + r;
        out[tok * CMOD + d] = x[tok * CMOD + d] + g * acc[mb][nb][r];
      }
  }
}

extern "C" void kernel_launch(void* const* d_in, const int* in_sizes, int n_in,
                              void* d_out, int out_size, void* d_ws, size_t ws_size,
                              hipStream_t stream) {
  const float* x       = (const float*)d_in[0];
  const float* q_a_w   = (const float*)d_in[1];
  const float* q_bias  = (const float*)d_in[2];
  const float* q_b_w   = (const float*)d_in[3];
  const float* kv_a_w  = (const float*)d_in[4];
  const float* kv_bias = (const float*)d_in[5];
  const float* k_w     = (const float*)d_in[6];
  const float* v_w     = (const float*)d_in[7];
  const float* o_w     = (const float*)d_in[8];
  const float* norm_w  = (const float*)d_in[9];
  const float* gamma   = (const float*)d_in[10];
  char* ws = (char*)d_ws;
  unsigned short* W    = (unsigned short*)(ws + OFF_W);
  unsigned short* OW   = (unsigned short*)(ws + OFF_OW);
  float*          BIAS = (float*)(ws + OFF_BIAS);
  unsigned short* Q    = (unsigned short*)(ws + OFF_Q);
  unsigned short* Kw   = (unsigned short*)(ws + OFF_K);
  unsigned short* Vw   = (unsigned short*)(ws + OFF_V);
  unsigned short* Y    = (unsigned short*)(ws + OFF_Y);
  float* out = (float*)d_out;

  k0_weights<<<256, 256, 0, stream>>>(q_a_w, q_bias, q_b_w, kv_a_w, kv_bias,
                                      k_w, v_w, o_w, W, OW, BIAS);
  k1_ln_qkv<<<256, 256, 0, stream>>>(x, norm_w, W, BIAS, Q, Kw, Vw);
  k2_attn<<<dim3(16, 32), 256, 0, stream>>>(Q, Kw, Vw, Y);
  k3_oproj<<<256, 256, 0, stream>>>(Y, OW, x, gamma, out);
}